// Round 8
// baseline (180.428 us; speedup 1.0000x reference)
//
#include <hip/hip_runtime.h>
#include <hip/hip_bf16.h>

typedef float f4 __attribute__((ext_vector_type(4)));
typedef short bf16x8 __attribute__((ext_vector_type(8)));

#define D 2048
#define RANK 16
#define NT1 256
#define NT2 256

__device__ __forceinline__ short bf16_of(float x) {
    return __builtin_bit_cast(short, __float2bfloat16(x));
}

__device__ __forceinline__ bf16x8 cvt8(f4 lo, f4 hi) {
    bf16x8 r;
    r[0] = bf16_of(lo.x); r[1] = bf16_of(lo.y);
    r[2] = bf16_of(lo.z); r[3] = bf16_of(lo.w);
    r[4] = bf16_of(hi.x); r[5] = bf16_of(hi.y);
    r[6] = bf16_of(hi.z); r[7] = bf16_of(hi.w);
    return r;
}

__device__ __forceinline__ float bf2f(short s) {
    return __uint_as_float(((unsigned)(unsigned short)s) << 16);
}

__device__ __forceinline__ void barrier_lgkm() {
    asm volatile("s_waitcnt lgkmcnt(0)" ::: "memory");
    __builtin_amdgcn_s_barrier();
}

// ============ k1: rank-partials, wave-autonomous, barrier-free ==============
// Block = 256 thr = 4 waves; block owns one 16-row tile; wave ks owns the
// K-slice [ks*512, ks*512+512). Per wave: 64 independent f4 loads feeding a
// 2-chain MFMA (reduction happens in the matrix pipe -- no shfl, no LDS, no
// barrier), then ONE coalesced 1KB partial store. Waves never wait on each
// other -> loads stay continuously in flight (the R1-R7 plateau was waves
// parked at block barriers holding zero outstanding loads).
__global__ __launch_bounds__(NT1, 4)
void lora_k1(const float* __restrict__ h, const float* __restrict__ B,
             float* __restrict__ ws) {
    const int tid  = threadIdx.x;
    const int ks   = tid >> 6;          // wave = K-slice
    const int lane = tid & 63;
    const int m16  = lane & 15;
    const int kg   = lane >> 4;
    const long tile = blockIdx.x;
    const long row0 = tile * 16;

    const float* pB = B + (long)m16 * D + ks * 512 + kg * 8;
    const float* pH = h + (row0 + m16) * D + ks * 512 + kg * 8;

    f4 a0 = {0.f, 0.f, 0.f, 0.f}, a1 = {0.f, 0.f, 0.f, 0.f};
#pragma unroll
    for (int s = 0; s < 8; ++s) {
        f4 bl = *(const f4*)(pB + s * 32);
        f4 bh = *(const f4*)(pB + s * 32 + 4);
        f4 hl = *(const f4*)(pH + s * 32);
        f4 hh = *(const f4*)(pH + s * 32 + 4);
        a0 = __builtin_amdgcn_mfma_f32_16x16x32_bf16(
            cvt8(bl, bh), cvt8(hl, hh), a0, 0, 0, 0);
    }
#pragma unroll
    for (int s = 8; s < 16; ++s) {
        f4 bl = *(const f4*)(pB + s * 32);
        f4 bh = *(const f4*)(pB + s * 32 + 4);
        f4 hl = *(const f4*)(pH + s * 32);
        f4 hh = *(const f4*)(pH + s * 32 + 4);
        a1 = __builtin_amdgcn_mfma_f32_16x16x32_bf16(
            cvt8(bl, bh), cvt8(hl, hh), a1, 0, 0, 0);
    }
    const f4 acc = a0 + a1;
    // lane holds ranks kg*4+i of row m16 -> ws[tile][ks][row][rank], f4 store
    *(f4*)(ws + tile * 1024 + ks * 256 + m16 * 16 + kg * 4) = acc;
}

// ============ k2: out = t · A^T, write-streamer =============================
// Block = 256 thr owns one 16-row tile x all 2048 e. Tiny prologue (4KB
// partial read -> LDS sum, 2 cheap barriers), then an uninterrupted stream:
// 32 NT f4 stores/thread (1KB contiguous per wave-instr), A as bf16 regs,
// t[row] from LDS broadcast. 4096 waves, no mid-stream barriers.
__global__ __launch_bounds__(NT2, 4)
void lora_k2(const float* __restrict__ ws, const float* __restrict__ A,
             float* __restrict__ out) {
    const int tid  = threadIdx.x;
    const int wave = tid >> 6;
    const int lane = tid & 63;
    const long tile = blockIdx.x;
    const long row0 = tile * 16;

    // ---- A slices (bf16, 16 VGPR) for this thread's 2 e-quads ----
    bf16x8 Abf[2][4][2];
    int e0s[2];
#pragma unroll
    for (int si = 0; si < 2; ++si) {
        const int e0 = (wave * 2 + si) * 256 + lane * 4;
        e0s[si] = e0;
#pragma unroll
        for (int j = 0; j < 4; ++j) {
            const float* pa = A + (long)(e0 + j) * RANK;
            f4 q0 = *(const f4*)(pa);
            f4 q1 = *(const f4*)(pa + 4);
            f4 q2 = *(const f4*)(pa + 8);
            f4 q3 = *(const f4*)(pa + 12);
            Abf[si][j][0] = cvt8(q0, q1);
            Abf[si][j][1] = cvt8(q2, q3);
        }
    }

    // ---- stage partials: thread t loads f4 #t of this tile's 4KB ----
    __shared__ f4 pbuf[4][16][4];   // [ks][row][rank-quad]
    __shared__ f4 tsum[16][4];
    pbuf[tid >> 6][(tid >> 2) & 15][tid & 3] =
        *(const f4*)(ws + tile * 1024 + tid * 4);
    barrier_lgkm();
    if (tid < 64) {
        const int r = tid >> 2, q = tid & 3;
        tsum[r][q] = pbuf[0][r][q] + pbuf[1][r][q] + pbuf[2][r][q] +
                     pbuf[3][r][q];
    }
    barrier_lgkm();

    // ---- stream: 16 rows x 2 segments, NT f4 stores ----
#pragma unroll 2
    for (int r = 0; r < 16; ++r) {
        const f4 t0 = tsum[r][0], t1 = tsum[r][1];
        const f4 t2 = tsum[r][2], t3 = tsum[r][3];
        float* po = out + (row0 + r) * D;
#pragma unroll
        for (int si = 0; si < 2; ++si) {
            f4 res;
#pragma unroll
            for (int j = 0; j < 4; ++j) {
                const bf16x8 lo = Abf[si][j][0], hi = Abf[si][j][1];
                float v;
                v  = t0.x * bf2f(lo[0]) + t0.y * bf2f(lo[1]) +
                     t0.z * bf2f(lo[2]) + t0.w * bf2f(lo[3]);
                v += t1.x * bf2f(lo[4]) + t1.y * bf2f(lo[5]) +
                     t1.z * bf2f(lo[6]) + t1.w * bf2f(lo[7]);
                v += t2.x * bf2f(hi[0]) + t2.y * bf2f(hi[1]) +
                     t2.z * bf2f(hi[2]) + t2.w * bf2f(hi[3]);
                v += t3.x * bf2f(hi[4]) + t3.y * bf2f(hi[5]) +
                     t3.z * bf2f(hi[6]) + t3.w * bf2f(hi[7]);
                res[j] = v;
            }
            __builtin_nontemporal_store(res, (f4*)(po + e0s[si]));
        }
    }
}

// ============ fallback (ws too small): round-7 fused kernel =================
__global__ __launch_bounds__(512, 4)
void lora_v7(const float* __restrict__ h, const float* __restrict__ A,
             const float* __restrict__ B, float* __restrict__ out) {
    const int tid  = threadIdx.x;
    const int wave = tid >> 6;
    const int lane = tid & 63;
    const int m16  = lane & 15;
    const int kg   = lane >> 4;
    const long row0 = (long)blockIdx.x * 16;

    __shared__ f4 ldsT[8][16][4];
    __shared__ f4 tt[16][4];

    bf16x8 Abf[4][2];
#pragma unroll
    for (int j = 0; j < 4; ++j) {
        const float* pa = A + (long)(tid * 4 + j) * RANK;
        f4 q0 = *(const f4*)(pa);
        f4 q1 = *(const f4*)(pa + 4);
        f4 q2 = *(const f4*)(pa + 8);
        f4 q3 = *(const f4*)(pa + 12);
        Abf[j][0] = cvt8(q0, q1);
        Abf[j][1] = cvt8(q2, q3);
    }

    const float* pB = B + (long)m16 * D + wave * 256 + kg * 8;
    bf16x8 Bb[8];
#pragma unroll
    for (int s = 0; s < 8; ++s) {
        f4 b0 = *(const f4*)(pB + s * 32);
        f4 b1 = *(const f4*)(pB + s * 32 + 4);
        Bb[s] = cvt8(b0, b1);
    }

    const float* ph = h + (row0 + m16) * D + wave * 256 + kg * 8;
    f4 hv[16];
#pragma unroll
    for (int s = 0; s < 8; ++s) {
        hv[2 * s]     = *(const f4*)(ph + s * 32);
        hv[2 * s + 1] = *(const f4*)(ph + s * 32 + 4);
    }
    f4 a0 = {0.f, 0.f, 0.f, 0.f}, a1 = {0.f, 0.f, 0.f, 0.f};
#pragma unroll
    for (int s = 0; s < 4; ++s)
        a0 = __builtin_amdgcn_mfma_f32_16x16x32_bf16(
            Bb[s], cvt8(hv[2 * s], hv[2 * s + 1]), a0, 0, 0, 0);
#pragma unroll
    for (int s = 4; s < 8; ++s)
        a1 = __builtin_amdgcn_mfma_f32_16x16x32_bf16(
            Bb[s], cvt8(hv[2 * s], hv[2 * s + 1]), a1, 0, 0, 0);
    ldsT[wave][m16][kg] = a0 + a1;

    barrier_lgkm();
    if (tid < 64) {
        const int r = tid >> 2, q = tid & 3;
        f4 s = ldsT[0][r][q];
#pragma unroll
        for (int w = 1; w < 8; ++w) s += ldsT[w][r][q];
        tt[r][q] = s;
    }
    barrier_lgkm();

    float* po = out + row0 * D + tid * 4;
#pragma unroll 4
    for (int r = 0; r < 16; ++r) {
        const f4 t0 = tt[r][0], t1 = tt[r][1];
        const f4 t2 = tt[r][2], t3 = tt[r][3];
        f4 res;
#pragma unroll
        for (int j = 0; j < 4; ++j) {
            const bf16x8 lo = Abf[j][0], hi = Abf[j][1];
            float v;
            v  = t0.x * bf2f(lo[0]) + t0.y * bf2f(lo[1]) +
                 t0.z * bf2f(lo[2]) + t0.w * bf2f(lo[3]);
            v += t1.x * bf2f(lo[4]) + t1.y * bf2f(lo[5]) +
                 t1.z * bf2f(lo[6]) + t1.w * bf2f(lo[7]);
            v += t2.x * bf2f(hi[0]) + t2.y * bf2f(hi[1]) +
                 t2.z * bf2f(hi[2]) + t2.w * bf2f(hi[3]);
            v += t3.x * bf2f(hi[4]) + t3.y * bf2f(hi[5]) +
                 t3.z * bf2f(hi[6]) + t3.w * bf2f(hi[7]);
            res[j] = v;
        }
        __builtin_nontemporal_store(res, (f4*)(po + (long)r * D));
    }
}

extern "C" void kernel_launch(void* const* d_in, const int* in_sizes, int n_in,
                              void* d_out, int out_size, void* d_ws,
                              size_t ws_size, hipStream_t stream) {
    const float* h = (const float*)d_in[0];
    const float* A = (const float*)d_in[1];
    const float* B = (const float*)d_in[2];
    float* out = (float*)d_out;

    const int n_rows = in_sizes[0] / D;           // 16384
    const int tiles  = n_rows / 16;               // 1024
    const size_t ws_needed = (size_t)tiles * 1024 * sizeof(float);  // 4 MB

    if (ws_size >= ws_needed) {
        float* ws = (float*)d_ws;
        hipLaunchKernelGGL(lora_k1, dim3(tiles), dim3(NT1), 0, stream,
                           h, B, ws);
        hipLaunchKernelGGL(lora_k2, dim3(tiles), dim3(NT2), 0, stream,
                           ws, A, out);
    } else {
        hipLaunchKernelGGL(lora_v7, dim3(tiles), dim3(512), 0, stream,
                           h, A, B, out);
    }
}

// Round 9
// 94.425 us; speedup vs baseline: 1.9108x; 1.9108x over previous
//
#include <hip/hip_runtime.h>
#include <hip/hip_bf16.h>

typedef float f4 __attribute__((ext_vector_type(4)));
typedef short bf16x8 __attribute__((ext_vector_type(8)));

#define D 2048
#define RANK 16
#define NTHREADS 512
#define GRID 256
#define TROWS 8

__device__ __forceinline__ short bf16_of(float x) {
    return __builtin_bit_cast(short, __float2bfloat16(x));
}

__device__ __forceinline__ bf16x8 cvt8(f4 lo, f4 hi) {
    bf16x8 r;
    r[0] = bf16_of(lo.x); r[1] = bf16_of(lo.y);
    r[2] = bf16_of(lo.z); r[3] = bf16_of(lo.w);
    r[4] = bf16_of(hi.x); r[5] = bf16_of(hi.y);
    r[6] = bf16_of(hi.z); r[7] = bf16_of(hi.w);
    return r;
}

__device__ __forceinline__ float dot4(f4 a, f4 b) {
    return a.x * b.x + a.y * b.y + a.z * b.z + a.w * b.w;
}

// LDS-drain-only barrier: global loads/stores stay in flight across it.
__device__ __forceinline__ void barrier_lgkm() {
    asm volatile("s_waitcnt lgkmcnt(0)" ::: "memory");
    __builtin_amdgcn_s_barrier();
}

// Persistent fused LoRA: out = h @ (A@B)^T through rank-16.
// grid = 256 blocks (1/CU), each block loops over `iters` 8-row tiles:
//   issue h-prefetch(t+1) -> MFMA phase1(t) -> lgkm-bar -> merge ->
//   lgkm-bar -> phase2 stores(t) -> cvt prefetched h
// A (fp32) and B (bf16) fragments are loaded ONCE and pinned register-
// resident with "+v" asm (loop-carried => allocator cannot rematerialize;
// rounds 1/3/5 showed it otherwise re-loads them every tile).
// Phase1 uses the verified MFMA map; 8-row tiles duplicate rows across
// lanes 8-15 (m16&7) -- MFMA util is 0.5%, the waste is free, and L1
// merges the duplicate loads within each instruction.
__global__ __launch_bounds__(NTHREADS, 1)
void lora_persist(const float* __restrict__ h, const float* __restrict__ A,
                  const float* __restrict__ B, float* __restrict__ out,
                  int iters) {
    const int tid  = threadIdx.x;
    const int wave = tid >> 6;
    const int lane = tid & 63;
    const int m16  = lane & 15;
    const int kg   = lane >> 4;
    const int bid  = blockIdx.x;

    __shared__ f4 ldsT[2][8][16][4];   // [buf][wave][row(dup)][rank-quad]
    __shared__ f4 tt[2][8][4];         // [buf][row][rank-quad], fp32

    // ---- A rows for this thread's e-quad (fp32, 64 VGPR, pinned) ----
    f4 Af[4][4];
#pragma unroll
    for (int j = 0; j < 4; ++j)
#pragma unroll
        for (int q = 0; q < 4; ++q)
            Af[j][q] = *(const f4*)(A + (long)(tid * 4 + j) * RANK + q * 4);

    // ---- B fragment, wave K-slice [wave*256,+256) (bf16, 32 VGPR) ----
    const float* pB = B + (long)m16 * D + wave * 256 + kg * 8;
    bf16x8 Bb[8];
#pragma unroll
    for (int s = 0; s < 8; ++s)
        Bb[s] = cvt8(*(const f4*)(pB + s * 32), *(const f4*)(pB + s * 32 + 4));

    // per-lane h offset within a tile (rows duplicated across m16 8-15)
    const long hoff = (long)(m16 & 7) * D + wave * 256 + kg * 8;

    // ---- prologue: load + convert h(tile0) ----
    f4 hf[16];
    {
        const float* ph = h + (long)bid * TROWS * D + hoff;
#pragma unroll
        for (int s = 0; s < 8; ++s) {
            hf[2 * s]     = *(const f4*)(ph + s * 32);
            hf[2 * s + 1] = *(const f4*)(ph + s * 32 + 4);
        }
    }
    bf16x8 hb[8];
#pragma unroll
    for (int s = 0; s < 8; ++s) hb[s] = cvt8(hf[2 * s], hf[2 * s + 1]);

    for (int t = 0; t < iters; ++t) {
        const int buf = t & 1;
        const long tile = (long)t * GRID + bid;

        // 1. issue h prefetch for tile t+1 (stays in flight across barriers)
        if (t + 1 < iters) {
            const float* pn =
                h + ((long)(t + 1) * GRID + bid) * TROWS * D + hoff;
#pragma unroll
            for (int s = 0; s < 8; ++s) {
                hf[2 * s]     = *(const f4*)(pn + s * 32);
                hf[2 * s + 1] = *(const f4*)(pn + s * 32 + 4);
            }
        }

        // 2. phase1 MFMA (two chains), T-partials -> LDS
        f4 a0 = {0.f, 0.f, 0.f, 0.f}, a1 = {0.f, 0.f, 0.f, 0.f};
#pragma unroll
        for (int s = 0; s < 4; ++s)
            a0 = __builtin_amdgcn_mfma_f32_16x16x32_bf16(Bb[s], hb[s], a0,
                                                         0, 0, 0);
#pragma unroll
        for (int s = 4; s < 8; ++s)
            a1 = __builtin_amdgcn_mfma_f32_16x16x32_bf16(Bb[s], hb[s], a1,
                                                         0, 0, 0);
        ldsT[buf][wave][m16][kg] = a0 + a1;

        barrier_lgkm();                 // ldsT[buf] visible
        if (tid < 32) {
            const int r = tid >> 2, q = tid & 3;
            f4 s = ldsT[buf][0][r][q];
#pragma unroll
            for (int w = 1; w < 8; ++w) s += ldsT[buf][w][r][q];
            tt[buf][r][q] = s;
        }
        barrier_lgkm();                 // tt[buf] visible

        // 3. phase2: 8 rows, coalesced NT f4 stores (wave = 1KB contiguous)
        float* po = out + tile * TROWS * D + tid * 4;
#pragma unroll
        for (int r = 0; r < TROWS; ++r) {
            const f4 t0 = tt[buf][r][0], t1 = tt[buf][r][1];
            const f4 t2 = tt[buf][r][2], t3 = tt[buf][r][3];
            f4 res;
            res.x = dot4(t0, Af[0][0]) + dot4(t1, Af[0][1]) +
                    dot4(t2, Af[0][2]) + dot4(t3, Af[0][3]);
            res.y = dot4(t0, Af[1][0]) + dot4(t1, Af[1][1]) +
                    dot4(t2, Af[1][2]) + dot4(t3, Af[1][3]);
            res.z = dot4(t0, Af[2][0]) + dot4(t1, Af[2][1]) +
                    dot4(t2, Af[2][2]) + dot4(t3, Af[2][3]);
            res.w = dot4(t0, Af[3][0]) + dot4(t1, Af[3][1]) +
                    dot4(t2, Af[3][2]) + dot4(t3, Af[3][3]);
            __builtin_nontemporal_store(res, (f4*)(po + (long)r * D));
        }

        // 4. convert prefetched h (compiler inserts counted vmcnt: waits
        //    only for the loads, which are older than the stores)
        if (t + 1 < iters) {
#pragma unroll
            for (int s = 0; s < 8; ++s) hb[s] = cvt8(hf[2 * s], hf[2 * s + 1]);
        }

        // 5. pin A/B fragments: "+v" makes them loop-carried register
        //    state -- the allocator cannot sink/rematerialize the loads.
        asm volatile("" : "+v"(Bb[0]), "+v"(Bb[1]), "+v"(Bb[2]), "+v"(Bb[3]),
                          "+v"(Bb[4]), "+v"(Bb[5]), "+v"(Bb[6]), "+v"(Bb[7]));
        asm volatile("" : "+v"(Af[0][0]), "+v"(Af[0][1]), "+v"(Af[0][2]),
                          "+v"(Af[0][3]), "+v"(Af[1][0]), "+v"(Af[1][1]),
                          "+v"(Af[1][2]), "+v"(Af[1][3]), "+v"(Af[2][0]),
                          "+v"(Af[2][1]), "+v"(Af[2][2]), "+v"(Af[2][3]),
                          "+v"(Af[3][0]), "+v"(Af[3][1]), "+v"(Af[3][2]),
                          "+v"(Af[3][3]));
    }
}

extern "C" void kernel_launch(void* const* d_in, const int* in_sizes, int n_in,
                              void* d_out, int out_size, void* d_ws,
                              size_t ws_size, hipStream_t stream) {
    const float* h = (const float*)d_in[0];
    const float* A = (const float*)d_in[1];
    const float* B = (const float*)d_in[2];
    float* out = (float*)d_out;

    const int n_rows = in_sizes[0] / D;          // 16384
    const int iters  = n_rows / (GRID * TROWS);  // 8

    hipLaunchKernelGGL(lora_persist, dim3(GRID), dim3(NTHREADS), 0, stream,
                       h, A, B, out, iters);
}

// Round 10
// 85.153 us; speedup vs baseline: 2.1189x; 1.1089x over previous
//
#include <hip/hip_runtime.h>
#include <hip/hip_bf16.h>

typedef float f4 __attribute__((ext_vector_type(4)));
typedef short bf16x8 __attribute__((ext_vector_type(8)));

#define D 2048
#define RANK 16
#define NTHR 512      // 8 waves
#define ROWS_PER_BLOCK 32
#define NSUB 8        // 8 subtiles x 4 rows

__device__ __forceinline__ short bf16_of(float x) {
    return __builtin_bit_cast(short, __float2bfloat16(x));
}

__device__ __forceinline__ bf16x8 cvt8(f4 lo, f4 hi) {
    bf16x8 r;
    r[0] = bf16_of(lo.x); r[1] = bf16_of(lo.y);
    r[2] = bf16_of(lo.z); r[3] = bf16_of(lo.w);
    r[4] = bf16_of(hi.x); r[5] = bf16_of(hi.y);
    r[6] = bf16_of(hi.z); r[7] = bf16_of(hi.w);
    return r;
}

__device__ __forceinline__ float bf2f(short s) {
    return __uint_as_float(((unsigned)(unsigned short)s) << 16);
}

// LDS-drain-only barrier (orders ds ops; leaves global loads in flight)
__device__ __forceinline__ void barrier_lgkm() {
    asm volatile("s_waitcnt lgkmcnt(0)" ::: "memory");
    __builtin_amdgcn_s_barrier();
}

// out = h @ (A@B)^T via rank-16. LDS-DMA pipelined (T3/T4 pattern):
// per subtile: issue DMA(t+1) -> vmcnt(8) [DMA(t+1)+stores stay in flight]
// -> barrier -> MFMA phase1 from LDS -> merge -> NT stores.
// In-flight bytes live in LDS (64 KB/CU), not VGPRs -> no spill, 2 blk/CU.
__global__ __launch_bounds__(NTHR, 4)
void lora_dma(const float* __restrict__ h, const float* __restrict__ A,
              const float* __restrict__ B, float* __restrict__ out) {
    __shared__ float hbuf[2][4 * D];    // 2 x 32 KB, [row][col] linear+swz
    __shared__ f4 ldsT[8][16][4];       // per-wave T partials
    __shared__ f4 tt[4][4];             // merged t[row][rank-quad]

    const int tid  = threadIdx.x;
    const int w    = tid >> 6;
    const int lane = tid & 63;
    const int m16  = lane & 15;
    const int kg   = lane >> 4;
    const int row  = m16 & 3;           // subtile h-row (dup x4 across m16)
    const long row0 = (long)blockIdx.x * ROWS_PER_BLOCK;

    // ---- A slice as bf16 (16 VGPR): Abf[j][k] = ranks k*8..+7 of e=tid*4+j
    bf16x8 Abf[4][2];
#pragma unroll
    for (int j = 0; j < 4; ++j) {
        const float* pa = A + (long)(tid * 4 + j) * RANK;
        Abf[j][0] = cvt8(*(const f4*)(pa), *(const f4*)(pa + 4));
        Abf[j][1] = cvt8(*(const f4*)(pa + 8), *(const f4*)(pa + 12));
    }

    // ---- B fragment bf16 (32 VGPR), wave K-window [w*256, +256) ----
    const float* pB = B + (long)m16 * D + w * 256 + kg * 8;
    bf16x8 Bb[8];
#pragma unroll
    for (int s = 0; s < 8; ++s)
        Bb[s] = cvt8(*(const f4*)(pB + s * 32), *(const f4*)(pB + s * 32 + 4));

    // ---- DMA: wave w loads half-row (w&1) of subtile-row (w>>1) ----
    // LDS linear dest; global source pre-swizzled by rxor so that the
    // 4-row-dup ds_reads below are bank-conflict-free (rule #21 pattern).
    const int rxor = (w >> 1) & 3;
    const int glane = (lane ^ rxor) * 4;          // 16B-unit lane permute

#define DMA_SUBTILE(bsel, st)                                                  \
    {                                                                          \
        const float* g_ = h + (row0 + (long)(st) * 4 + (w >> 1)) * D +         \
                          (w & 1) * 1024 + glane;                              \
        float* l_ = &hbuf[(bsel)][0] + w * 1024;                               \
        _Pragma("unroll") for (int i = 0; i < 4; ++i)                          \
            __builtin_amdgcn_global_load_lds(                                  \
                (const __attribute__((address_space(1))) void*)(g_ + i * 256), \
                (__attribute__((address_space(3))) void*)(l_ + i * 256),       \
                16, 0, 0);                                                     \
    }

    // prologue: stage subtile 0, drain, sync
    DMA_SUBTILE(0, 0)
    asm volatile("s_waitcnt vmcnt(0)" ::: "memory");
    __builtin_amdgcn_s_barrier();

    const long rsh = row << 4;            // read-side swizzle XOR (bytes)
    const long rbase = (long)row * 8192;  // row offset in bytes

#pragma unroll 1
    for (int t = 0; t < NSUB; ++t) {
        // A: issue next-subtile DMA; B: counted wait retiring only DMA(t)
        if (t + 1 < NSUB) {
            DMA_SUBTILE((t + 1) & 1, t + 1)
            asm volatile("s_waitcnt vmcnt(8)" ::: "memory");
        } else {
            asm volatile("s_waitcnt vmcnt(4)" ::: "memory");
        }
        __builtin_amdgcn_s_barrier();

        // phase1: MFMA over this wave's K-window, h from LDS (swizzled)
        const char* hb = (const char*)&hbuf[t & 1][0];
        f4 ac0 = {0.f, 0.f, 0.f, 0.f}, ac1 = {0.f, 0.f, 0.f, 0.f};
#pragma unroll
        for (int s = 0; s < 8; ++s) {
            const long c0 = (long)w * 1024 + kg * 32 + s * 128;
            f4 v0 = *(const f4*)(hb + rbase + (c0 ^ rsh));
            f4 v1 = *(const f4*)(hb + rbase + ((c0 + 16) ^ rsh));
            bf16x8 hv = cvt8(v0, v1);
            if (s < 4)
                ac0 = __builtin_amdgcn_mfma_f32_16x16x32_bf16(Bb[s], hv, ac0,
                                                              0, 0, 0);
            else
                ac1 = __builtin_amdgcn_mfma_f32_16x16x32_bf16(Bb[s], hv, ac1,
                                                              0, 0, 0);
        }
        ldsT[w][m16][kg] = ac0 + ac1;

        barrier_lgkm();                   // ldsT ready (also: all ds_reads
                                          // of hbuf[t&1] complete -> safe to
                                          // DMA into it next iteration)
        if (tid < 16) {
            const int r = tid >> 2, q = tid & 3;
            f4 s = ldsT[0][r][q];
#pragma unroll
            for (int ww = 1; ww < 8; ++ww) s += ldsT[ww][r][q];
            tt[r][q] = s;
        }
        barrier_lgkm();                   // tt ready

        // phase2: 4 rows, A from bf16 regs, coalesced NT f4 stores
        float* po = out + (row0 + (long)t * 4) * D + tid * 4;
#pragma unroll
        for (int r = 0; r < 4; ++r) {
            const f4 t0 = tt[r][0], t1 = tt[r][1];
            const f4 t2 = tt[r][2], t3 = tt[r][3];
            f4 res;
#pragma unroll
            for (int j = 0; j < 4; ++j) {
                const bf16x8 lo = Abf[j][0], hi = Abf[j][1];
                float v;
                v  = t0.x * bf2f(lo[0]) + t0.y * bf2f(lo[1]) +
                     t0.z * bf2f(lo[2]) + t0.w * bf2f(lo[3]);
                v += t1.x * bf2f(lo[4]) + t1.y * bf2f(lo[5]) +
                     t1.z * bf2f(lo[6]) + t1.w * bf2f(lo[7]);
                v += t2.x * bf2f(hi[0]) + t2.y * bf2f(hi[1]) +
                     t2.z * bf2f(hi[2]) + t2.w * bf2f(hi[3]);
                v += t3.x * bf2f(hi[4]) + t3.y * bf2f(hi[5]) +
                     t3.z * bf2f(hi[6]) + t3.w * bf2f(hi[7]);
                res[j] = v;
            }
            __builtin_nontemporal_store(res, (f4*)(po + (long)r * D));
        }
    }
#undef DMA_SUBTILE
}

extern "C" void kernel_launch(void* const* d_in, const int* in_sizes, int n_in,
                              void* d_out, int out_size, void* d_ws,
                              size_t ws_size, hipStream_t stream) {
    const float* h = (const float*)d_in[0];
    const float* A = (const float*)d_in[1];
    const float* B = (const float*)d_in[2];
    float* out = (float*)d_out;

    const int n_rows = in_sizes[0] / D;             // 16384
    const int blocks = n_rows / ROWS_PER_BLOCK;     // 512

    hipLaunchKernelGGL(lora_dma, dim3(blocks), dim3(NTHR), 0, stream,
                       h, A, B, out);
}